// Round 3
// baseline (6538.109 us; speedup 1.0000x reference)
//
#include <hip/hip_runtime.h>

// ---------------- problem constants ----------------
// S=512 seq, B=64 batch, I=256 in, H=1024 hidden, 4H=4096 gates
// Wx = [W1 W3 W5 W7] (input side), Wh = [W2 W4 W6 W8] (hidden side)
// out: h_seq (512,64,1024) fp32, then h_final (64,1024), c_final (64,1024)

// ---------------- workspace layout (bytes) ----------------
#define OFF_XB    0ul          // bf16 x      [512][64][256]   = 16 MiB
#define OFF_WXP   16777216ul   // bf16 Wx^T   [4096][256]      =  2 MiB (packed [col][k])
#define OFF_WHP   18874368ul   // bf16 Wh^T   [4096][1024]     =  8 MiB (packed [col][k], PRE-SWIZZLED)
#define OFF_BIAS  27262976ul   // f32 bx+bh   [4096]
#define OFF_HBUF  27279360ul   // u32 tagged h {bf16<<16|tag} [2][64][1024] = 512 KiB

typedef __attribute__((ext_vector_type(8))) __bf16 bf16x8;
typedef __attribute__((ext_vector_type(4))) float  floatx4;

struct KPtrs { const float* p[17]; };

__device__ __forceinline__ unsigned short f2bf(float f) {  // fp32 -> bf16 RTN-even
  unsigned int u = __float_as_uint(f);
  u += 0x7fffu + ((u >> 16) & 1u);
  return (unsigned short)(u >> 16);
}

__device__ __forceinline__ bf16x8 ld16(const unsigned short* p) {
  return *(const bf16x8*)p;   // cached global_load_dwordx4
}

__device__ __forceinline__ float fsig(float x) {
  return __builtin_amdgcn_rcpf(1.f + __expf(-x));
}
__device__ __forceinline__ float ftanh(float x) {
  return 1.f - 2.f * __builtin_amdgcn_rcpf(1.f + __expf(2.f * x));
}

// L3-coherent (agent-scope, L2-bypassing) relaxed 8B atomic load
__device__ __forceinline__ unsigned long long lduc64(const unsigned int* p) {
  return __hip_atomic_load((const unsigned long long*)p,
                           __ATOMIC_RELAXED, __HIP_MEMORY_SCOPE_AGENT);
}

// all four u64's two 16-bit tag fields must equal tt's tag (tt = t | t<<32)
__device__ __forceinline__ bool tags4(const unsigned long long* v, unsigned long long tt) {
  const unsigned long long TM = 0x0000FFFF0000FFFFull;
  unsigned long long d = (v[0] ^ tt) | (v[1] ^ tt) | (v[2] ^ tt) | (v[3] ^ tt);
  return (d & TM) == 0ull;
}

// strip tags: 4 u64 (8 tagged u32, h in high 16 bits) -> 8 packed bf16
__device__ __forceinline__ bf16x8 unpack4(const unsigned long long* v) {
  unsigned int w[4];
#pragma unroll
  for (int i = 0; i < 4; ++i) {
    unsigned int lo = (unsigned int)v[i];
    unsigned int hi = (unsigned int)(v[i] >> 32);
    w[i] = __builtin_amdgcn_perm(hi, lo, 0x07060302);  // {hi.hi16, lo.hi16}
  }
  bf16x8 r;
  __builtin_memcpy(&r, w, 16);
  return r;
}

// ---------------- pack/convert + state init ----------------
__global__ void pack_kernel(KPtrs P, unsigned char* ws) {
  unsigned short* xb   = (unsigned short*)(ws + OFF_XB);
  unsigned short* wxp  = (unsigned short*)(ws + OFF_WXP);
  unsigned short* whp  = (unsigned short*)(ws + OFF_WHP);
  float*          bias = (float*)(ws + OFF_BIAS);
  unsigned int*   hb32 = (unsigned int*)(ws + OFF_HBUF);
  const float* x = P.p[0];

  const long tid = (long)blockIdx.x * blockDim.x + threadIdx.x;
  const long nth = (long)gridDim.x * blockDim.x;

  for (long e = tid; e < 8388608l; e += nth)       // x -> bf16, same flat layout
    xb[e] = f2bf(x[e]);
  for (long e = tid; e < 1048576l; e += nth) {     // Wx packed [col][k]
    int c = (int)(e >> 8), i = (int)(e & 255);
    int gg = c >> 10, j = c & 1023;
    wxp[e] = f2bf(P.p[1 + 4 * gg][i * 1024 + j]);  // W1,W3,W5,W7
  }
  // Wh packed [col][k], PRE-SWIZZLED: element (c,k) stored at k ^ ((c&7)<<3)
  // so the lstm kernel's LDS staging is a plain linear copy and ds_read_b128
  // with the same XOR on the read side is bank-conflict-free.
  for (long e = tid; e < 4194304l; e += nth) {
    int c = (int)(e >> 10), k = (int)(e & 1023);
    int gg = c >> 10, j = c & 1023;
    long dst = ((long)c << 10) | (long)(k ^ ((c & 7) << 3));
    whp[dst] = f2bf(P.p[3 + 4 * gg][k * 1024 + j]);  // W2,W4,W6,W8
  }
  for (long e = tid; e < 4096l; e += nth) {        // bx + bh
    int gg = (int)(e >> 10), j = (int)(e & 1023);
    bias[e] = P.p[2 + 4 * gg][j] + P.p[4 + 4 * gg][j];
  }
  // tagged h double buffer = 0  (h=0, tag=0 == "h_{-1} ready"; UC stores -> L3)
  for (long e = tid; e < 131072l; e += nth)
    __hip_atomic_store(&hb32[e], 0u, __ATOMIC_RELAXED, __HIP_MEMORY_SCOPE_AGENT);
}

// issue / re-issue the full 64-u64 tagged h burst (all loads in flight at once)
#define H_BURST()                                            \
  do {                                                       \
    _Pragma("unroll")                                        \
    for (int kk = 0; kk < 8; ++kk) {                         \
      _Pragma("unroll")                                      \
      for (int i = 0; i < 4; ++i) {                          \
        hv0[kk * 4 + i] = lduc64(hb0 + kk * 32 + 2 * i);     \
        hv1[kk * 4 + i] = lduc64(hb1 + kk * 32 + 2 * i);     \
      }                                                      \
    }                                                        \
  } while (0)

// ---------------- persistent fused LSTM ----------------
// 128 blocks (PROVEN co-resident: half of 256 CUs at 1 block/CU) =
//   2 batch-groups (32 batches) x 64 hidden-slices (16 units x 4 gates).
// Self-validating tagged h: u32 {bf16<<16 | (t+1)}, depth-2 parity buffer.
//   safety: block B publishes tag-(t+3) into parity buffer t&1 only after its
//   step-(t+2) tag checks observed tag-(t+2) from ALL 64 group members; a
//   member publishes tag-(t+2) only after consuming its tag-(t+1) reads ->
//   no overwrite-while-read. No fences, no flags, no ack barriers.
// Per step: speculative 64-u64 burst + per-producer hint poll; on hint miss,
// poll then re-burst ALL loads in parallel (never serialized retries).
__global__ void __launch_bounds__(256, 1)
lstm_kernel(const unsigned char* __restrict__ ws, float* __restrict__ out) {
  const unsigned short* xb   = (const unsigned short*)(ws + OFF_XB);
  const unsigned short* wxp  = (const unsigned short*)(ws + OFF_WXP);
  const unsigned short* whp  = (const unsigned short*)(ws + OFF_WHP);
  const float*          bias = (const float*)(ws + OFF_BIAS);
  unsigned int*         hbuf = (unsigned int*)(ws + OFF_HBUF);

  const int tid = threadIdx.x;
  const int wv = tid >> 6, lane = tid & 63;
  const int r = lane & 15, q = lane >> 4;          // MFMA frag row/col + k-quad
  const int s = blockIdx.x & 63, gb = blockIdx.x >> 6;

  __shared__ unsigned short whl[65536];            // 128 KiB swizzled Wh slice
  __shared__ float pc[4][4][64][4];                // 16 KiB cross-wave reduce

  // ---- stage Wh slice into LDS (linear copy; swizzle pre-baked in whp) ----
  for (int ch = tid; ch < 8192; ch += 256) {
    const int le = ch * 8;                         // bf16 element index in whl
    const int rl = le >> 10, k8 = le & 1023;       // local row 0..63
    const int cg = (rl >> 4) * 1024 + s * 16 + (rl & 15);   // global gate col
    *(bf16x8*)&whl[le] = ld16(whp + (long)cg * 1024 + k8);
  }

  // ---- Wx fragments in registers (loop-invariant, 32 VGPR) ----
  bf16x8 wxf[4][2];
#pragma unroll
  for (int nt = 0; nt < 4; ++nt) {
    const int c = nt * 1024 + s * 16 + r;
#pragma unroll
    for (int kk = 0; kk < 2; ++kk)
      wxf[nt][kk] = ld16(wxp + (long)c * 256 + wv * 64 + kk * 32 + q * 8);
  }

  // epilogue mapping: thread -> (batches eb, eb+16 ; hidden col ej)
  const int ej = tid & 15, eb = tid >> 4;
  const int lidx = ej | ((eb >> 2) << 4), rg = eb & 3;   // C-frag coords
  float bs[4];
#pragma unroll
  for (int gt = 0; gt < 4; ++gt) bs[gt] = bias[gt * 1024 + s * 16 + ej];

  const unsigned short* xa0 = xb + (long)(gb * 32 + r) * 256 + q * 8;
  const int hrow    = (gb * 32 + r) * 1024 + wv * 256 + q * 8;   // u32 index
  // hint: rows gb*32+{0,8,16,24} x one word per producer s' in this wave's k-slice
  const int hintoff = (gb * 32 + ((lane >> 4) << 3)) * 1024 + (wv * 16 + (lane & 15)) * 16;
  const int rs = (r & 7) << 3;                     // LDS XOR swizzle term

  float cst[2] = {0.f, 0.f};
  __syncthreads();                                 // whl staged

  for (int t = 0; t < 512; ++t) {
    const unsigned int* hpar = hbuf + (long)((t - 1) & 1) * 65536;
    const unsigned long long tg = (unsigned int)t;
    const unsigned long long tt = tg | (tg << 32);
    const unsigned long long TM = 0x0000FFFF0000FFFFull;

    // ---- issue x loads first (oldest in vmcnt queue), then hint ----
    const unsigned short* xaT = xa0 + (long)t * 16384;
    bf16x8 xv[2][2];
#pragma unroll
    for (int kk = 0; kk < 2; ++kk) {
      xv[0][kk] = ld16(xaT + wv * 64 + kk * 32);
      xv[1][kk] = ld16(xaT + 16 * 256 + wv * 64 + kk * 32);
    }
    const unsigned int* hip_ = hpar + hintoff;
    unsigned long long hw = lduc64(hip_);

    floatx4 acc[2][4];
#pragma unroll
    for (int mt = 0; mt < 2; ++mt)
#pragma unroll
      for (int nt = 0; nt < 4; ++nt) acc[mt][nt] = (floatx4){0.f, 0.f, 0.f, 0.f};

    // ---- x-side K (waits only on xv loads; hint + burst stay in flight) ----
#pragma unroll
    for (int kk = 0; kk < 2; ++kk)
#pragma unroll
      for (int nt = 0; nt < 4; ++nt) {
        acc[0][nt] = __builtin_amdgcn_mfma_f32_16x16x32_bf16(xv[0][kk], wxf[nt][kk], acc[0][nt], 0, 0, 0);
        acc[1][nt] = __builtin_amdgcn_mfma_f32_16x16x32_bf16(xv[1][kk], wxf[nt][kk], acc[1][nt], 0, 0, 0);
      }

    // ---- speculative burst: ALL 64 tagged u64 loads in flight at once ----
    const unsigned int* hb0 = hpar + hrow;
    const unsigned int* hb1 = hb0 + 16 * 1024;
    unsigned long long hv0[32], hv1[32];
    H_BURST();
    asm volatile("" ::: "memory");

    // ---- hint check: wait until this wave's 16 producers have published ----
    if (!__all(((hw ^ tt) & TM) == 0ull)) {
      do {
        __builtin_amdgcn_s_sleep(1);
        hw = lduc64(hip_);
      } while (!__all(((hw ^ tt) & TM) == 0ull));
      H_BURST();                    // data was mid-publish: re-issue in parallel
      asm volatile("" ::: "memory");
    }

    // ---- h-side K: per-chunk tag check (steady state: passes first try) ----
#pragma unroll
    for (int kk = 0; kk < 8; ++kk) {
      bf16x8 wb[4];
      const int el = wv * 256 + ((kk * 32 + q * 8) ^ rs);
#pragma unroll
      for (int nt = 0; nt < 4; ++nt)
        wb[nt] = *(const bf16x8*)&whl[(nt * 16 + r) * 1024 + el];
      while (!__all(tags4(&hv0[kk * 4], tt))) {
#pragma unroll
        for (int i = 0; i < 4; ++i)
          hv0[kk * 4 + i] = lduc64(hb0 + kk * 32 + 2 * i);
      }
      bf16x8 a0 = unpack4(&hv0[kk * 4]);
#pragma unroll
      for (int nt = 0; nt < 4; ++nt)
        acc[0][nt] = __builtin_amdgcn_mfma_f32_16x16x32_bf16(a0, wb[nt], acc[0][nt], 0, 0, 0);
      while (!__all(tags4(&hv1[kk * 4], tt))) {
#pragma unroll
        for (int i = 0; i < 4; ++i)
          hv1[kk * 4 + i] = lduc64(hb1 + kk * 32 + 2 * i);
      }
      bf16x8 a1 = unpack4(&hv1[kk * 4]);
#pragma unroll
      for (int nt = 0; nt < 4; ++nt)
        acc[1][nt] = __builtin_amdgcn_mfma_f32_16x16x32_bf16(a1, wb[nt], acc[1][nt], 0, 0, 0);
    }

    // ---- two-phase cross-wave reduce + gates + publish (144 KiB LDS cap) ----
#pragma unroll
    for (int e = 0; e < 2; ++e) {
      __syncthreads();              // prior phase's pc reads complete
#pragma unroll
      for (int nt = 0; nt < 4; ++nt)
        *(floatx4*)(&pc[wv][nt][lane][0]) = acc[e][nt];
      __syncthreads();

      float gs[4];
#pragma unroll
      for (int gt = 0; gt < 4; ++gt)
        gs[gt] = bs[gt] + pc[0][gt][lidx][rg] + pc[1][gt][lidx][rg] +
                 pc[2][gt][lidx][rg] + pc[3][gt][lidx][rg];
      const float f = fsig(gs[0]), ii = fsig(gs[1]), o = fsig(gs[2]);
      const float cd = ftanh(gs[3]);
      cst[e] = f * cst[e] + ii * cd;
      const float hvv = o * ftanh(cst[e]);

      // publish tagged h_t (UC store; no ack, no flag, no barrier)
      unsigned short hb16 = f2bf(hvv);
      unsigned short nbv = (unsigned short)__shfl_xor((int)hb16, 1, 64);
      if ((ej & 1) == 0) {
        const unsigned int tagw = (unsigned int)(t + 1);
        unsigned long long pv =
            ((unsigned long long)((((unsigned int)hb16) << 16) | tagw)) |
            (((unsigned long long)((((unsigned int)nbv) << 16) | tagw)) << 32);
        unsigned long long* hp = (unsigned long long*)(hbuf + (long)(t & 1) * 65536 +
            (long)(gb * 32 + e * 16 + eb) * 1024 + s * 16 + ej);
        __hip_atomic_store(hp, pv, __ATOMIC_RELAXED, __HIP_MEMORY_SCOPE_AGENT);
      }

      // h_seq / finals: normal cached stores (write-back; flushed at end)
      const long ob = (long)(gb * 32 + e * 16 + eb) * 1024 + s * 16 + ej;
      out[(long)t * 65536 + ob] = hvv;
      if (t == 511) {
        out[33554432l + ob] = hvv;
        out[33619968l + ob] = cst[e];
      }
    }
  }
}

extern "C" void kernel_launch(void* const* d_in, const int* in_sizes, int n_in,
                              void* d_out, int out_size, void* d_ws, size_t ws_size,
                              hipStream_t stream) {
  (void)in_sizes; (void)n_in; (void)out_size; (void)ws_size;
  KPtrs P;
  for (int i = 0; i < 17; ++i) P.p[i] = (const float*)d_in[i];
  pack_kernel<<<dim3(2048), dim3(256), 0, stream>>>(P, (unsigned char*)d_ws);
  lstm_kernel<<<dim3(128), dim3(256), 0, stream>>>((const unsigned char*)d_ws, (float*)d_out);
}

// Round 4
// 3702.314 us; speedup vs baseline: 1.7660x; 1.7660x over previous
//
#include <hip/hip_runtime.h>

// ---------------- problem constants ----------------
// S=512 seq, B=64 batch, I=256 in, H=1024 hidden, 4H=4096 gates
// Wx = [W1 W3 W5 W7] (input side), Wh = [W2 W4 W6 W8] (hidden side)
// out: h_seq (512,64,1024) fp32, then h_final (64,1024), c_final (64,1024)

// ---------------- workspace layout (bytes) ----------------
#define OFF_XB    0ul          // bf16 x      [512][64][256]   = 16 MiB
#define OFF_WXP   16777216ul   // bf16 Wx^T   [4096][256]      =  2 MiB (packed [col][k])
#define OFF_WHP   18874368ul   // bf16 Wh^T   [4096][1024]     =  8 MiB (packed [col][k], PRE-SWIZZLED)
#define OFF_BIAS  27262976ul   // f32 bx+bh   [4096]
#define OFF_HBUF  27279360ul   // bf16 h      [2][64][1024]    = 256 KiB double buffer
#define OFF_FLG   27541504ul   // int flags   [128]  (plain UC stores, no RMW)

typedef __attribute__((ext_vector_type(8))) __bf16 bf16x8;
typedef __attribute__((ext_vector_type(4))) float  floatx4;

struct KPtrs { const float* p[17]; };

__device__ __forceinline__ unsigned short f2bf(float f) {  // fp32 -> bf16 RTN-even
  unsigned int u = __float_as_uint(f);
  u += 0x7fffu + ((u >> 16) & 1u);
  return (unsigned short)(u >> 16);
}

__device__ __forceinline__ bf16x8 ld16(const unsigned short* p) {
  return *(const bf16x8*)p;   // cached global_load_dwordx4
}

// L3-coherent (agent-scope, L2-bypassing) 16B load as 2x relaxed u64 atomic loads
__device__ __forceinline__ bf16x8 ldsys16(const unsigned short* p) {
  unsigned long long a =
      __hip_atomic_load((const unsigned long long*)p,       __ATOMIC_RELAXED, __HIP_MEMORY_SCOPE_AGENT);
  unsigned long long b =
      __hip_atomic_load((const unsigned long long*)(p + 4), __ATOMIC_RELAXED, __HIP_MEMORY_SCOPE_AGENT);
  unsigned long long arr[2] = {a, b};
  bf16x8 r;
  __builtin_memcpy(&r, arr, 16);
  return r;
}

__device__ __forceinline__ float fsig(float x) {
  return __builtin_amdgcn_rcpf(1.f + __expf(-x));
}
__device__ __forceinline__ float ftanh(float x) {
  return 1.f - 2.f * __builtin_amdgcn_rcpf(1.f + __expf(2.f * x));
}

// ---------------- pack/convert + state init ----------------
__global__ void pack_kernel(KPtrs P, unsigned char* ws) {
  unsigned short* xb   = (unsigned short*)(ws + OFF_XB);
  unsigned short* wxp  = (unsigned short*)(ws + OFF_WXP);
  unsigned short* whp  = (unsigned short*)(ws + OFF_WHP);
  float*          bias = (float*)(ws + OFF_BIAS);
  unsigned int*   hb32 = (unsigned int*)(ws + OFF_HBUF);
  int*            flg  = (int*)(ws + OFF_FLG);
  const float* x = P.p[0];

  const long tid = (long)blockIdx.x * blockDim.x + threadIdx.x;
  const long nth = (long)gridDim.x * blockDim.x;

  for (long e = tid; e < 8388608l; e += nth)       // x -> bf16, same flat layout
    xb[e] = f2bf(x[e]);
  for (long e = tid; e < 1048576l; e += nth) {     // Wx packed [col][k]
    int c = (int)(e >> 8), i = (int)(e & 255);
    int gg = c >> 10, j = c & 1023;
    wxp[e] = f2bf(P.p[1 + 4 * gg][i * 1024 + j]);  // W1,W3,W5,W7
  }
  // Wh packed [col][k], PRE-SWIZZLED: element (c,k) stored at k ^ ((c&7)<<3)
  // so LDS staging in the lstm kernel is a plain linear copy and the
  // ds_read_b128 with the same XOR on the read side is bank-balanced.
  for (long e = tid; e < 4194304l; e += nth) {
    int c = (int)(e >> 10), k = (int)(e & 1023);
    int gg = c >> 10, j = c & 1023;
    long dst = ((long)c << 10) | (long)(k ^ ((c & 7) << 3));
    whp[dst] = f2bf(P.p[3 + 4 * gg][k * 1024 + j]);  // W2,W4,W6,W8
  }
  for (long e = tid; e < 4096l; e += nth) {        // bx + bh
    int gg = (int)(e >> 10), j = (int)(e & 1023);
    bias[e] = P.p[2 + 4 * gg][j] + P.p[4 + 4 * gg][j];
  }
  // h double buffer = 0 (UC stores: land at the L3 coherence point)
  for (long e = tid; e < 65536l; e += nth)
    __hip_atomic_store(&hb32[e], 0u, __ATOMIC_RELAXED, __HIP_MEMORY_SCOPE_AGENT);
  // flags = -1  (h_{-1} ready)
  for (long e = tid; e < 128l; e += nth)
    __hip_atomic_store(&flg[e], -1, __ATOMIC_RELAXED, __HIP_MEMORY_SCOPE_AGENT);
}

// ---------------- persistent fused LSTM ----------------
// 128 blocks (proven co-resident) = 2 batch-groups (32 batches) x 64
// hidden-slices (16 units x 4 gates). PROVEN flag protocol (baseline, 2920us):
// UC h + per-block flag, no fences, no RMW. Changes vs baseline:
//  (a) Wh streamed from LDS (swizzled; baseline silently demoted it from regs
//      and re-fetched via L1/L2 every step),
//  (b) freed registers spent on a guaranteed-parallel h-load burst: all 16
//      ldsys16 issued into a register array BEFORE any h-MFMA (one UC round
//      trip instead of compiler-chunked serialized groups),
//  (c) flag wait covers only the own batch-group's 64 flags (was all 128).
__global__ void __launch_bounds__(256, 1)
lstm_kernel(const unsigned char* __restrict__ ws, float* __restrict__ out) {
  const unsigned short* xb   = (const unsigned short*)(ws + OFF_XB);
  const unsigned short* wxp  = (const unsigned short*)(ws + OFF_WXP);
  const unsigned short* whp  = (const unsigned short*)(ws + OFF_WHP);
  const float*          bias = (const float*)(ws + OFF_BIAS);
  unsigned short*       hbuf = (unsigned short*)(ws + OFF_HBUF);
  int*                  flg  = (int*)(ws + OFF_FLG);

  const int tid = threadIdx.x;
  const int wv = tid >> 6, lane = tid & 63;
  const int r = lane & 15, q = lane >> 4;          // MFMA frag row + k-quad
  const int s = blockIdx.x & 63, g = blockIdx.x >> 6;

  __shared__ unsigned short whl[65536];            // 128 KiB swizzled Wh slice
  __shared__ float pc[4][4][64][4];                // 16 KiB cross-wave reduce

  // ---- stage Wh slice into LDS (linear copy; swizzle pre-baked in whp) ----
  for (int ch = tid; ch < 8192; ch += 256) {
    const int le = ch * 8;                         // bf16 element index in whl
    const int rl = le >> 10, k8 = le & 1023;       // local row 0..63
    const int cg = (rl >> 4) * 1024 + s * 16 + (rl & 15);   // global gate col
    *(bf16x8*)&whl[le] = ld16(whp + (long)cg * 1024 + k8);
  }

  // ---- Wx fragments in registers (loop-invariant, 32 VGPR) ----
  bf16x8 wxf[4][2];
#pragma unroll
  for (int nt = 0; nt < 4; ++nt) {
    const int c = nt * 1024 + s * 16 + r;
#pragma unroll
    for (int kk = 0; kk < 2; ++kk)
      wxf[nt][kk] = ld16(wxp + (long)c * 256 + wv * 64 + kk * 32 + q * 8);
  }

  // epilogue mapping: thread -> (batches eb, eb+16 ; hidden col ej)
  const int ej = tid & 15, eb = tid >> 4;
  const int lidx = ej | ((eb >> 2) << 4), rg = eb & 3;   // C-frag coords
  float bs[4];
#pragma unroll
  for (int gt = 0; gt < 4; ++gt) bs[gt] = bias[gt * 1024 + s * 16 + ej];

  const unsigned short* xa0 = xb + (long)(g * 32 + r) * 256 + q * 8;
  const int rs = (r & 7) << 3;                     // LDS XOR swizzle term
  const unsigned long long* fl64 = (const unsigned long long*)flg;
  const int fidx = g * 32 + (lane & 31);           // own group's 64 flags only

  float cst[2] = {0.f, 0.f};
  __syncthreads();                                 // whl staged

  for (int t = 0; t < 512; ++t) {
    // ---- flag load first (oldest in flight), then x loads ----
    unsigned long long fv =
        __hip_atomic_load(&fl64[fidx], __ATOMIC_RELAXED, __HIP_MEMORY_SCOPE_AGENT);

    const unsigned short* xaT = xa0 + (long)t * 16384;
    bf16x8 xv[2][2];
#pragma unroll
    for (int kk = 0; kk < 2; ++kk) {
      xv[0][kk] = ld16(xaT + wv * 64 + kk * 32);
      xv[1][kk] = ld16(xaT + 16 * 256 + wv * 64 + kk * 32);
    }

    floatx4 acc[2][4];
#pragma unroll
    for (int mt = 0; mt < 2; ++mt)
#pragma unroll
      for (int nt = 0; nt < 4; ++nt) acc[mt][nt] = (floatx4){0.f, 0.f, 0.f, 0.f};

    // ---- x-side K (hides the flag round trip) ----
#pragma unroll
    for (int kk = 0; kk < 2; ++kk)
#pragma unroll
      for (int nt = 0; nt < 4; ++nt) {
        acc[0][nt] = __builtin_amdgcn_mfma_f32_16x16x32_bf16(xv[0][kk], wxf[nt][kk], acc[0][nt], 0, 0, 0);
        acc[1][nt] = __builtin_amdgcn_mfma_f32_16x16x32_bf16(xv[1][kk], wxf[nt][kk], acc[1][nt], 0, 0, 0);
      }

    // ---- wait: own group's 64 flags >= t-1 (no barrier) ----
    {
      const int need = t - 1;
      while (!(((int)(unsigned int)fv >= need) && ((int)(unsigned int)(fv >> 32) >= need) ?
               __all(1) : __all(0))) {
        __builtin_amdgcn_s_sleep(1);
        fv = __hip_atomic_load(&fl64[fidx], __ATOMIC_RELAXED, __HIP_MEMORY_SCOPE_AGENT);
      }
    }
    asm volatile("" ::: "memory");

    // ---- h burst: ALL 16 ldsys16 (32 u64) in flight before any h-MFMA ----
    const unsigned short* ha =
        hbuf + (long)((t - 1) & 1) * 65536 + ((long)g * 32 + r) * 1024 + q * 8;
    bf16x8 hv0[8], hv1[8];
#pragma unroll
    for (int kk = 0; kk < 8; ++kk) {
      const int k0 = wv * 256 + kk * 32;
      hv0[kk] = ldsys16(ha + k0);
      hv1[kk] = ldsys16(ha + 16 * 1024 + k0);
    }

    // ---- h-side K from LDS weights ----
#pragma unroll
    for (int kk = 0; kk < 8; ++kk) {
      bf16x8 wb[4];
      const int el = wv * 256 + ((kk * 32 + q * 8) ^ rs);
#pragma unroll
      for (int nt = 0; nt < 4; ++nt)
        wb[nt] = *(const bf16x8*)&whl[(nt * 16 + r) * 1024 + el];
#pragma unroll
      for (int nt = 0; nt < 4; ++nt) {
        acc[0][nt] = __builtin_amdgcn_mfma_f32_16x16x32_bf16(hv0[kk], wb[nt], acc[0][nt], 0, 0, 0);
        acc[1][nt] = __builtin_amdgcn_mfma_f32_16x16x32_bf16(hv1[kk], wb[nt], acc[1][nt], 0, 0, 0);
      }
    }

    // ---- two-phase cross-wave reduce + gates + publish ----
    float hvv[2];
#pragma unroll
    for (int e = 0; e < 2; ++e) {
      __syncthreads();              // prior phase's pc reads complete
#pragma unroll
      for (int nt = 0; nt < 4; ++nt)
        *(floatx4*)(&pc[wv][nt][lane][0]) = acc[e][nt];
      __syncthreads();

      float gs[4];
#pragma unroll
      for (int gt = 0; gt < 4; ++gt)
        gs[gt] = bs[gt] + pc[0][gt][lidx][rg] + pc[1][gt][lidx][rg] +
                 pc[2][gt][lidx][rg] + pc[3][gt][lidx][rg];
      const float f = fsig(gs[0]), ii = fsig(gs[1]), o = fsig(gs[2]);
      const float cd = ftanh(gs[3]);
      cst[e] = f * cst[e] + ii * cd;
      hvv[e] = o * ftanh(cst[e]);

      // publish h_t slice (bf16, UC write-through to L3)
      unsigned short hb16 = f2bf(hvv[e]);
      unsigned short nbv = (unsigned short)__shfl_xor((int)hb16, 1, 64);
      if ((ej & 1) == 0) {
        unsigned int pv = (unsigned int)hb16 | ((unsigned int)nbv << 16);
        unsigned int* hp = (unsigned int*)(hbuf + (long)(t & 1) * 65536 +
            (long)(g * 32 + e * 16 + eb) * 1024 + s * 16 + ej);
        __hip_atomic_store(hp, pv, __ATOMIC_RELAXED, __HIP_MEMORY_SCOPE_AGENT);
      }

      // h_seq / finals: normal cached stores (write-back; flushed at end)
      const long ob = (long)(g * 32 + e * 16 + eb) * 1024 + s * 16 + ej;
      out[(long)t * 65536 + ob] = hvv[e];
      if (t == 511) {
        out[33554432l + ob] = hvv[e];
        out[33619968l + ob] = cst[e];
      }
    }

    __syncthreads();  // vmcnt(0): all h stores acked at L3 before flag store
    if (tid == 0)     // plain UC flag store — no RMW, no fence
      __hip_atomic_store(&flg[blockIdx.x], t, __ATOMIC_RELAXED, __HIP_MEMORY_SCOPE_AGENT);
  }
}

extern "C" void kernel_launch(void* const* d_in, const int* in_sizes, int n_in,
                              void* d_out, int out_size, void* d_ws, size_t ws_size,
                              hipStream_t stream) {
  (void)in_sizes; (void)n_in; (void)out_size; (void)ws_size;
  KPtrs P;
  for (int i = 0; i < 17; ++i) P.p[i] = (const float*)d_in[i];
  pack_kernel<<<dim3(2048), dim3(256), 0, stream>>>(P, (unsigned char*)d_ws);
  lstm_kernel<<<dim3(128), dim3(256), 0, stream>>>((const unsigned char*)d_ws, (float*)d_out);
}